// Round 1
// baseline (236.054 us; speedup 1.0000x reference)
//
#include <hip/hip_runtime.h>
#include <hip/hip_bf16.h>

typedef __attribute__((ext_vector_type(4))) float f32x4;
typedef __attribute__((ext_vector_type(8))) short bf16x8;
typedef __attribute__((ext_vector_type(4))) unsigned short u16x4;
typedef __attribute__((ext_vector_type(8))) unsigned short u16x8;

__device__ __forceinline__ unsigned short f2bf(float f) {
    unsigned int u = __builtin_bit_cast(unsigned int, f);
    u += 0x7fffu + ((u >> 16) & 1u);   // RNE; inputs are finite, no NaN handling needed
    return (unsigned short)(u >> 16);
}

// swizzle in ushort units: rows are 64 ushorts (128 B); XOR bits 3..5 with row&7
#define SWZ(i) ((i) ^ ((((i) >> 6) & 7) << 3))

constexpr int BM = 128, BN = 128, BK = 64;

__global__ void transpose_cvt(const float* __restrict__ src,
                              unsigned short* __restrict__ dst,
                              int rows, int cols) {
    int idx = blockIdx.x * 256 + threadIdx.x;     // idx = c*rows + r
    int c = idx / rows;
    int r = idx - c * rows;
    dst[idx] = f2bf(src[(size_t)r * cols + c]);
}

// D = A(f32, MxK) @ B (given as Bt bf16, NxK) + epilogue
// EPI 0: D(bf16, transposed NxM) = acc + epi[row*lde+col]   (T = input@W1 + W2)
// EPI 1: D(f32)  = acc + bias[col]                          (C0 = x@W3 + b)
// EPI 2: D(f32)  = acc + epi[row*lde+col]                   (out = adj@T + C0)
template<int EPI>
__global__ __launch_bounds__(512, 2)
void gemm_k(const float* __restrict__ A, long lda,
            const unsigned short* __restrict__ Bt, long ldb,
            int K,
            const float* __restrict__ epi, long lde,
            const float* __restrict__ bias,
            void* __restrict__ Dptr, long ldd) {
    __shared__ unsigned short sA[2][BM * BK];
    __shared__ unsigned short sB[2][BN * BK];

    const int t = threadIdx.x;          // 0..511
    const int l = t & 63;
    const int w = t >> 6;               // wave 0..7
    const int wm = w >> 2;              // 0..1  (64-row slab)
    const int wn = w & 3;               // 0..3  (32-col slab)
    const long n0 = (long)blockIdx.x * BN;   // n fastest for L2 reuse of A panel
    const long m0 = (long)blockIdx.y * BM;

    f32x4 acc[4][2];
    #pragma unroll
    for (int m = 0; m < 4; ++m)
        #pragma unroll
        for (int n = 0; n < 2; ++n)
            acc[m][n] = {0.f, 0.f, 0.f, 0.f};

    f32x4 av[4];
    u16x8 bv[2];

    auto load_glb = [&](int kt) {
        const long k0 = (long)kt * BK;
        #pragma unroll
        for (int r = 0; r < 4; ++r) {
            int e = r * 2048 + t * 4;
            int row = e >> 6, k = e & 63;
            av[r] = *reinterpret_cast<const f32x4*>(&A[(m0 + row) * lda + k0 + k]);
        }
        #pragma unroll
        for (int r = 0; r < 2; ++r) {
            int e = r * 4096 + t * 8;
            int col = e >> 6, k = e & 63;
            bv[r] = *reinterpret_cast<const u16x8*>(&Bt[(n0 + col) * ldb + k0 + k]);
        }
    };

    auto write_lds = [&](int buf) {
        #pragma unroll
        for (int r = 0; r < 4; ++r) {
            int e = r * 2048 + t * 4;
            u16x4 wv;
            wv[0] = f2bf(av[r][0]);
            wv[1] = f2bf(av[r][1]);
            wv[2] = f2bf(av[r][2]);
            wv[3] = f2bf(av[r][3]);
            *reinterpret_cast<u16x4*>(&sA[buf][SWZ(e)]) = wv;
        }
        #pragma unroll
        for (int r = 0; r < 2; ++r) {
            int e = r * 4096 + t * 8;
            *reinterpret_cast<u16x8*>(&sB[buf][SWZ(e)]) = bv[r];
        }
    };

    auto compute = [&](int buf) {
        #pragma unroll
        for (int kk = 0; kk < BK; kk += 32) {
            bf16x8 af[4], bfr[2];
            const int kb = kk + ((l >> 4) << 3);
            #pragma unroll
            for (int m = 0; m < 4; ++m) {
                int row = wm * 64 + m * 16 + (l & 15);
                int idx = row * 64 + kb;
                af[m] = *reinterpret_cast<const bf16x8*>(&sA[buf][SWZ(idx)]);
            }
            #pragma unroll
            for (int n = 0; n < 2; ++n) {
                int col = wn * 32 + n * 16 + (l & 15);
                int idx = col * 64 + kb;
                bfr[n] = *reinterpret_cast<const bf16x8*>(&sB[buf][SWZ(idx)]);
            }
            #pragma unroll
            for (int m = 0; m < 4; ++m)
                #pragma unroll
                for (int n = 0; n < 2; ++n)
                    acc[m][n] = __builtin_amdgcn_mfma_f32_16x16x32_bf16(
                        af[m], bfr[n], acc[m][n], 0, 0, 0);
        }
    };

    // prologue
    load_glb(0);
    write_lds(0);
    __syncthreads();

    const int nk = K / BK;
    for (int kt = 0; kt < nk; ++kt) {
        const int cur = kt & 1;
        if (kt + 1 < nk) load_glb(kt + 1);   // issue early (latency hides under MFMA)
        compute(cur);
        if (kt + 1 < nk) write_lds(cur ^ 1); // write late, after compute
        __syncthreads();
    }

    // epilogue
    const int jrow = (l >> 4) * 4;
    #pragma unroll
    for (int m = 0; m < 4; ++m) {
        const long row = m0 + wm * 64 + m * 16 + jrow;
        #pragma unroll
        for (int n = 0; n < 2; ++n) {
            const long col = n0 + wn * 32 + n * 16 + (l & 15);
            f32x4 v = acc[m][n];
            if constexpr (EPI == 0) {
                u16x4 o;
                #pragma unroll
                for (int j = 0; j < 4; ++j)
                    o[j] = f2bf(v[j] + epi[(row + j) * lde + col]);
                // transposed bf16 store: D[col][row], 4 k-contiguous elems
                *reinterpret_cast<u16x4*>(&((unsigned short*)Dptr)[col * ldd + row]) = o;
            } else if constexpr (EPI == 1) {
                float b = bias[col];
                #pragma unroll
                for (int j = 0; j < 4; ++j)
                    ((float*)Dptr)[(row + j) * ldd + col] = v[j] + b;
            } else {
                #pragma unroll
                for (int j = 0; j < 4; ++j)
                    ((float*)Dptr)[(row + j) * ldd + col] =
                        v[j] + epi[(row + j) * lde + col];
            }
        }
    }
}

extern "C" void kernel_launch(void* const* d_in, const int* in_sizes, int n_in,
                              void* d_out, int out_size, void* d_ws, size_t ws_size,
                              hipStream_t stream) {
    const float* input  = (const float*)d_in[0];   // 8192 x 512
    const float* adj    = (const float*)d_in[1];   // 8192 x 8192
    const float* x      = (const float*)d_in[2];   // 8192 x 512
    const float* weight = (const float*)d_in[3];   // 9216 x 512
    const float* bias   = (const float*)d_in[4];   // 512

    const int N = 8192, IN_F = 512, NFEAT = 512, OUT_F = 512;
    float* out = (float*)d_out;

    // workspace layout (~25 MB)
    unsigned short* Tbt = (unsigned short*)d_ws;            // [512][8192] bf16 (T transposed)
    unsigned short* W1t = Tbt + (size_t)OUT_F * N;          // [512][512] bf16
    unsigned short* W3t = W1t + (size_t)OUT_F * IN_F;       // [512][512] bf16
    float* C0 = (float*)(W3t + (size_t)OUT_F * NFEAT);      // [8192][512] f32

    // W1t[n][k] = W1[k][n],  W3t[n][k] = W3[k][n]
    transpose_cvt<<<dim3((IN_F * OUT_F) / 256), dim3(256), 0, stream>>>(
        weight, W1t, IN_F, OUT_F);
    transpose_cvt<<<dim3((NFEAT * OUT_F) / 256), dim3(256), 0, stream>>>(
        weight + (size_t)(IN_F + N) * OUT_F, W3t, NFEAT, OUT_F);

    dim3 grid(OUT_F / BN, N / BM);  // (4, 64), n-tile fastest

    // T = input @ W1 + W2   -> Tbt (bf16, [OUT_F][N])
    gemm_k<0><<<grid, 512, 0, stream>>>(
        input, (long)IN_F, W1t, (long)IN_F, IN_F,
        weight + (size_t)IN_F * OUT_F, (long)OUT_F, nullptr,
        Tbt, (long)N);

    // C0 = x @ W3 + bias
    gemm_k<1><<<grid, 512, 0, stream>>>(
        x, (long)NFEAT, W3t, (long)NFEAT, NFEAT,
        nullptr, 0, bias,
        C0, (long)OUT_F);

    // out = adj @ T + C0
    gemm_k<2><<<grid, 512, 0, stream>>>(
        adj, (long)N, Tbt, (long)N, N,
        C0, (long)OUT_F, nullptr,
        out, (long)OUT_F);
}

// Round 2
// 185.634 us; speedup vs baseline: 1.2716x; 1.2716x over previous
//
#include <hip/hip_runtime.h>
#include <hip/hip_bf16.h>

typedef __attribute__((ext_vector_type(4))) float f32x4;
typedef __attribute__((ext_vector_type(8))) short bf16x8;
typedef __attribute__((ext_vector_type(4))) unsigned short u16x4;
typedef __attribute__((ext_vector_type(8))) unsigned short u16x8;

__device__ __forceinline__ unsigned short f2bf(float f) {
    unsigned int u = __builtin_bit_cast(unsigned int, f);
    u += 0x7fffu + ((u >> 16) & 1u);   // RNE; inputs finite
    return (unsigned short)(u >> 16);
}

// swizzle in ushort units: rows are 64 ushorts (128 B); XOR bits 3..5 with row&7
#define SWZ(i) ((i) ^ ((((i) >> 6) & 7) << 3))

constexpr int BM = 64, BN = 128, BK = 64;

__global__ void transpose_cvt(const float* __restrict__ src,
                              unsigned short* __restrict__ dst,
                              int rows, int cols) {
    int idx = blockIdx.x * 256 + threadIdx.x;     // idx = c*rows + r
    int c = idx / rows;
    int r = idx - c * rows;
    dst[idx] = f2bf(src[(size_t)r * cols + c]);
}

// D = A(f32, MxK) @ B (given as Bt bf16, NxK) + epilogue
// EPI 0: D(bf16, transposed NxM) = acc + epi[row*lde+col]   (T = input@W1 + W2)
// EPI 1: D(f32)  = acc + bias[col]                          (C0 = x@W3 + b)
// EPI 2: D(f32)  = acc + epi[row*lde+col]                   (out = adj@T + C0)
template<int EPI>
__global__ __launch_bounds__(512, 4)
void gemm_k(const float* __restrict__ A, long lda,
            const unsigned short* __restrict__ Bt, long ldb,
            int K,
            const float* __restrict__ epi, long lde,
            const float* __restrict__ bias,
            void* __restrict__ Dptr, long ldd) {
    __shared__ unsigned short sA[2][BM * BK];
    __shared__ unsigned short sB[2][BN * BK];

    const int t = threadIdx.x;          // 0..511
    const int l = t & 63;
    const int w = t >> 6;               // wave 0..7
    const int wm = w >> 2;              // 0..1  (32-row slab)
    const int wn = w & 3;               // 0..3  (32-col slab)

    // XCD-bijective swizzle: group all gridDim.x n-tiles of one m-panel on
    // one XCD (assumes hw round-robin lin%8 -> XCD; perf-only heuristic).
    int mt, nt;
    {
        int lin = blockIdx.y * gridDim.x + blockIdx.x;
        if ((gridDim.y & 7) == 0) {
            int xcd = lin & 7;
            int slot = lin >> 3;                 // [0, nblk/8)
            int ppx = gridDim.y >> 3;            // m-panels per XCD
            mt = xcd * ppx + slot / gridDim.x;
            nt = slot % gridDim.x;
        } else {
            mt = blockIdx.y; nt = blockIdx.x;
        }
    }
    const long m0 = (long)mt * BM;
    const long n0 = (long)nt * BN;

    f32x4 acc[2][2];
    #pragma unroll
    for (int m = 0; m < 2; ++m)
        #pragma unroll
        for (int n = 0; n < 2; ++n)
            acc[m][n] = {0.f, 0.f, 0.f, 0.f};

    // two named register stages (static indexing only — no runtime stage idx)
    f32x4 avA[2], avB[2];
    u16x8 bvA[2], bvB[2];

    auto load_glb = [&](int kt, f32x4* av, u16x8* bv) {
        const long k0 = (long)kt * BK;
        #pragma unroll
        for (int r = 0; r < 2; ++r) {            // A: 64x64 f32, 8 elem/thread
            int e = r * 2048 + t * 4;
            int row = e >> 6, k = e & 63;
            av[r] = *reinterpret_cast<const f32x4*>(&A[(m0 + row) * lda + k0 + k]);
        }
        #pragma unroll
        for (int r = 0; r < 2; ++r) {            // B: 128x64 bf16, 16 elem/thread
            int e = r * 4096 + t * 8;
            int col = e >> 6, k = e & 63;
            bv[r] = *reinterpret_cast<const u16x8*>(&Bt[(n0 + col) * ldb + k0 + k]);
        }
    };

    auto write_lds = [&](int buf, const f32x4* av, const u16x8* bv) {
        #pragma unroll
        for (int r = 0; r < 2; ++r) {
            int e = r * 2048 + t * 4;
            u16x4 wv;
            wv[0] = f2bf(av[r][0]);
            wv[1] = f2bf(av[r][1]);
            wv[2] = f2bf(av[r][2]);
            wv[3] = f2bf(av[r][3]);
            *reinterpret_cast<u16x4*>(&sA[buf][SWZ(e)]) = wv;
        }
        #pragma unroll
        for (int r = 0; r < 2; ++r) {
            int e = r * 4096 + t * 8;
            *reinterpret_cast<u16x8*>(&sB[buf][SWZ(e)]) = bv[r];
        }
    };

    auto compute = [&](int buf) {
        #pragma unroll
        for (int kk = 0; kk < BK; kk += 32) {
            bf16x8 af[2], bfr[2];
            const int kb = kk + ((l >> 4) << 3);
            #pragma unroll
            for (int m = 0; m < 2; ++m) {
                int row = wm * 32 + m * 16 + (l & 15);
                int idx = row * 64 + kb;
                af[m] = *reinterpret_cast<const bf16x8*>(&sA[buf][SWZ(idx)]);
            }
            #pragma unroll
            for (int n = 0; n < 2; ++n) {
                int col = wn * 32 + n * 16 + (l & 15);
                int idx = col * 64 + kb;
                bfr[n] = *reinterpret_cast<const bf16x8*>(&sB[buf][SWZ(idx)]);
            }
            #pragma unroll
            for (int m = 0; m < 2; ++m)
                #pragma unroll
                for (int n = 0; n < 2; ++n)
                    acc[m][n] = __builtin_amdgcn_mfma_f32_16x16x32_bf16(
                        af[m], bfr[n], acc[m][n], 0, 0, 0);
        }
    };

    // prologue: LDS0 <- tile0, regsB <- tile1
    load_glb(0, avA, bvA);
    write_lds(0, avA, bvA);
    load_glb(1, avB, bvB);
    __syncthreads();

    const int nk = K / BK;                        // even (128 or 8)
    for (int kt = 0; kt < nk; kt += 2) {
        // even phase: LDS0 = kt, regsB = kt+1
        if (kt + 2 < nk) load_glb(kt + 2, avA, bvA);   // ~2 phases of latency
        compute(0);
        write_lds(1, avB, bvB);
        __syncthreads();
        // odd phase: LDS1 = kt+1, regsA = kt+2
        if (kt + 3 < nk) load_glb(kt + 3, avB, bvB);
        compute(1);
        if (kt + 2 < nk) write_lds(0, avA, bvA);
        __syncthreads();
    }

    // epilogue
    const int jrow = (l >> 4) * 4;
    #pragma unroll
    for (int m = 0; m < 2; ++m) {
        const long row = m0 + wm * 32 + m * 16 + jrow;
        #pragma unroll
        for (int n = 0; n < 2; ++n) {
            const long col = n0 + wn * 32 + n * 16 + (l & 15);
            f32x4 v = acc[m][n];
            if constexpr (EPI == 0) {
                u16x4 o;
                #pragma unroll
                for (int j = 0; j < 4; ++j)
                    o[j] = f2bf(v[j] + epi[(row + j) * lde + col]);
                // transposed bf16 store: D[col][row], 4 k-contiguous elems
                *reinterpret_cast<u16x4*>(&((unsigned short*)Dptr)[col * ldd + row]) = o;
            } else if constexpr (EPI == 1) {
                float b = bias[col];
                #pragma unroll
                for (int j = 0; j < 4; ++j)
                    ((float*)Dptr)[(row + j) * ldd + col] = v[j] + b;
            } else {
                #pragma unroll
                for (int j = 0; j < 4; ++j)
                    ((float*)Dptr)[(row + j) * ldd + col] =
                        v[j] + epi[(row + j) * lde + col];
            }
        }
    }
}

extern "C" void kernel_launch(void* const* d_in, const int* in_sizes, int n_in,
                              void* d_out, int out_size, void* d_ws, size_t ws_size,
                              hipStream_t stream) {
    const float* input  = (const float*)d_in[0];   // 8192 x 512
    const float* adj    = (const float*)d_in[1];   // 8192 x 8192
    const float* x      = (const float*)d_in[2];   // 8192 x 512
    const float* weight = (const float*)d_in[3];   // 9216 x 512
    const float* bias   = (const float*)d_in[4];   // 512

    const int N = 8192, IN_F = 512, NFEAT = 512, OUT_F = 512;
    float* out = (float*)d_out;

    // workspace layout (~25 MB)
    unsigned short* Tbt = (unsigned short*)d_ws;            // [512][8192] bf16 (T transposed)
    unsigned short* W1t = Tbt + (size_t)OUT_F * N;          // [512][512] bf16
    unsigned short* W3t = W1t + (size_t)OUT_F * IN_F;       // [512][512] bf16
    float* C0 = (float*)(W3t + (size_t)OUT_F * NFEAT);      // [8192][512] f32

    transpose_cvt<<<dim3((IN_F * OUT_F) / 256), dim3(256), 0, stream>>>(
        weight, W1t, IN_F, OUT_F);
    transpose_cvt<<<dim3((NFEAT * OUT_F) / 256), dim3(256), 0, stream>>>(
        weight + (size_t)(IN_F + N) * OUT_F, W3t, NFEAT, OUT_F);

    dim3 grid(OUT_F / BN, N / BM);  // (4, 128) = 512 blocks -> 2 blocks/CU

    // T = input @ W1 + W2   -> Tbt (bf16, [OUT_F][N])
    gemm_k<0><<<grid, 512, 0, stream>>>(
        input, (long)IN_F, W1t, (long)IN_F, IN_F,
        weight + (size_t)IN_F * OUT_F, (long)OUT_F, nullptr,
        Tbt, (long)N);

    // C0 = x @ W3 + bias
    gemm_k<1><<<grid, 512, 0, stream>>>(
        x, (long)NFEAT, W3t, (long)NFEAT, NFEAT,
        nullptr, 0, bias,
        C0, (long)OUT_F);

    // out = adj @ T + C0
    gemm_k<2><<<grid, 512, 0, stream>>>(
        adj, (long)N, Tbt, (long)N, N,
        C0, (long)OUT_F, nullptr,
        out, (long)OUT_F);
}